// Round 1
// baseline (1120.700 us; speedup 1.0000x reference)
//
#include <hip/hip_runtime.h>
#include <math.h>

namespace {

constexpr int BATCH  = 16;
constexpr int SEQ    = 64;
constexpr int PDIM   = 256;
constexpr int DMODEL = 512;
constexpr int DINNER = 1024;
constexpr int DFF    = 16;
constexpr int DTRANK = 32;
constexpr int MROWS  = BATCH * SEQ;   // 1024

__device__ __forceinline__ float sigm(float x) { return 1.f / (1.f + __expf(-x)); }

enum { EPI_NONE = 0, EPI_BIAS_GELU, EPI_BIAS_SIGMOID, EPI_BIAS_MUL, EPI_ADD, EPI_BIAS_SOFTPLUS };

// C(M x N) = epi(A(M x K) @ W(N x K)^T); tiles 64x64, BK=16, 256 thr, 4x4/thread.
template <int EPI>
__global__ __launch_bounds__(256) void gemm_tn(
    const float* __restrict__ A, int lda,
    const float* __restrict__ W, int ldw,
    float* __restrict__ C, int ldc, int Kd,
    const float* __restrict__ bias, const float* __restrict__ extra)
{
    __shared__ float As[16][68];   // pad 68: float4-aligned rows, conflict-free
    __shared__ float Bs[16][68];
    const int tid = threadIdx.x;
    const int m0 = blockIdx.y * 64, n0 = blockIdx.x * 64;
    const int row = tid & 63, kg = tid >> 6;   // staging: row + k-group
    const int tr = tid >> 4, tc = tid & 15;    // compute: 4 rows, 4 cols per thread
    float acc[4][4] = {};
    const float* ap = A + (size_t)(m0 + row) * lda + kg * 4;
    const float* wp = W + (size_t)(n0 + row) * ldw + kg * 4;
    for (int k0 = 0; k0 < Kd; k0 += 16) {
        const float4 a4 = *(const float4*)(ap + k0);
        const float4 b4 = *(const float4*)(wp + k0);
        __syncthreads();
        As[kg * 4 + 0][row] = a4.x; As[kg * 4 + 1][row] = a4.y;
        As[kg * 4 + 2][row] = a4.z; As[kg * 4 + 3][row] = a4.w;
        Bs[kg * 4 + 0][row] = b4.x; Bs[kg * 4 + 1][row] = b4.y;
        Bs[kg * 4 + 2][row] = b4.z; Bs[kg * 4 + 3][row] = b4.w;
        __syncthreads();
#pragma unroll
        for (int k = 0; k < 16; k++) {
            const float4 av = *(const float4*)&As[k][tr * 4];
            const float4 bv = *(const float4*)&Bs[k][tc * 4];
            acc[0][0] = fmaf(av.x, bv.x, acc[0][0]);
            acc[0][1] = fmaf(av.x, bv.y, acc[0][1]);
            acc[0][2] = fmaf(av.x, bv.z, acc[0][2]);
            acc[0][3] = fmaf(av.x, bv.w, acc[0][3]);
            acc[1][0] = fmaf(av.y, bv.x, acc[1][0]);
            acc[1][1] = fmaf(av.y, bv.y, acc[1][1]);
            acc[1][2] = fmaf(av.y, bv.z, acc[1][2]);
            acc[1][3] = fmaf(av.y, bv.w, acc[1][3]);
            acc[2][0] = fmaf(av.z, bv.x, acc[2][0]);
            acc[2][1] = fmaf(av.z, bv.y, acc[2][1]);
            acc[2][2] = fmaf(av.z, bv.z, acc[2][2]);
            acc[2][3] = fmaf(av.z, bv.w, acc[2][3]);
            acc[3][0] = fmaf(av.w, bv.x, acc[3][0]);
            acc[3][1] = fmaf(av.w, bv.y, acc[3][1]);
            acc[3][2] = fmaf(av.w, bv.z, acc[3][2]);
            acc[3][3] = fmaf(av.w, bv.w, acc[3][3]);
        }
    }
#pragma unroll
    for (int i = 0; i < 4; i++) {
        const int mm = m0 + tr * 4 + i;
        const int nn = n0 + tc * 4;
        float4 v = make_float4(acc[i][0], acc[i][1], acc[i][2], acc[i][3]);
        if (EPI == EPI_BIAS_GELU || EPI == EPI_BIAS_SIGMOID ||
            EPI == EPI_BIAS_MUL || EPI == EPI_BIAS_SOFTPLUS) {
            const float4 b = *(const float4*)(bias + nn);
            v.x += b.x; v.y += b.y; v.z += b.z; v.w += b.w;
        }
        if (EPI == EPI_BIAS_GELU) {
            v.x = 0.5f * v.x * (1.f + erff(v.x * 0.70710678f));
            v.y = 0.5f * v.y * (1.f + erff(v.y * 0.70710678f));
            v.z = 0.5f * v.z * (1.f + erff(v.z * 0.70710678f));
            v.w = 0.5f * v.w * (1.f + erff(v.w * 0.70710678f));
        } else if (EPI == EPI_BIAS_SIGMOID) {
            v.x = sigm(v.x); v.y = sigm(v.y); v.z = sigm(v.z); v.w = sigm(v.w);
        } else if (EPI == EPI_BIAS_SOFTPLUS) {
            v.x = fmaxf(v.x, 0.f) + log1pf(__expf(-fabsf(v.x)));
            v.y = fmaxf(v.y, 0.f) + log1pf(__expf(-fabsf(v.y)));
            v.z = fmaxf(v.z, 0.f) + log1pf(__expf(-fabsf(v.z)));
            v.w = fmaxf(v.w, 0.f) + log1pf(__expf(-fabsf(v.w)));
        } else if (EPI == EPI_BIAS_MUL) {
            const float4 e = *(const float4*)(extra + (size_t)mm * ldc + nn);
            v.x *= e.x; v.y *= e.y; v.z *= e.z; v.w *= e.w;
        } else if (EPI == EPI_ADD) {
            const float4 e = *(const float4*)(extra + (size_t)mm * ldc + nn);
            v.x += e.x; v.y += e.y; v.z += e.z; v.w += e.w;
        }
        *(float4*)(C + (size_t)mm * ldc + nn) = v;
    }
}

// rmsnorm over rows of 512; one wave (64 lanes x 8 elems) per row, 4 rows/block.
__global__ __launch_bounds__(256) void rmsnorm_k(
    const float* __restrict__ in, const float* __restrict__ w, float* __restrict__ out)
{
    const int lane = threadIdx.x & 63;
    const int rowId = blockIdx.x * 4 + (threadIdx.x >> 6);
    const float* ip = in + (size_t)rowId * DMODEL + lane * 8;
    const float4 v1 = *(const float4*)ip;
    const float4 v2 = *(const float4*)(ip + 4);
    float ss = v1.x * v1.x + v1.y * v1.y + v1.z * v1.z + v1.w * v1.w
             + v2.x * v2.x + v2.y * v2.y + v2.z * v2.z + v2.w * v2.w;
#pragma unroll
    for (int off = 32; off > 0; off >>= 1) ss += __shfl_xor(ss, off, 64);
    const float rs = rsqrtf(ss * (1.f / 512.f) + 1e-5f);
    const float4 w1 = *(const float4*)(w + lane * 8);
    const float4 w2 = *(const float4*)(w + lane * 8 + 4);
    float* op = out + (size_t)rowId * DMODEL + lane * 8;
    *(float4*)op       = make_float4(v1.x * rs * w1.x, v1.y * rs * w1.y, v1.z * rs * w1.z, v1.w * rs * w1.w);
    *(float4*)(op + 4) = make_float4(v2.x * rs * w2.x, v2.y * rs * w2.y, v2.z * rs * w2.z, v2.w * rs * w2.w);
}

// Depthwise causal conv (D_CONV=4) + bias + silu. xr rows are 2048 wide (x part = cols 0..1023).
__global__ __launch_bounds__(256) void conv_silu_k(
    const float* __restrict__ xr, const float* __restrict__ cw,
    const float* __restrict__ cb, float* __restrict__ xc)
{
    const int idx = blockIdx.x * 256 + threadIdx.x;   // 0 .. 1024*1024
    const int d = idx & (DINNER - 1);
    const int m = idx >> 10;
    const int l = m & (SEQ - 1);
    const float4 w4 = *(const float4*)(cw + d * 4);
    const float wj[4] = { w4.x, w4.y, w4.z, w4.w };
    float acc = cb[d];
#pragma unroll
    for (int j = 0; j < 4; j++) {
        const int li = l + j - 3;
        if (li >= 0) acc += xr[(size_t)(m + j - 3) * 2048 + d] * wj[j];
    }
    xc[idx] = acc * sigm(acc);
}

// Selective scan + fused y *= silu(res). One thread per (b,d); 16 states in regs.
__global__ __launch_bounds__(256) void scan_k(
    const float* __restrict__ xc, const float* __restrict__ delta,
    const float* __restrict__ xdbl, const float* __restrict__ Alog,
    const float* __restrict__ Dp, const float* __restrict__ xr, float* __restrict__ y)
{
    const int b = blockIdx.x >> 2;
    const int d = ((blockIdx.x & 3) << 8) + threadIdx.x;
    __shared__ float Bs[SEQ][DFF];
    __shared__ float Cs[SEQ][DFF];
    for (int i = threadIdx.x; i < SEQ * DFF; i += 256) {
        const int l = i >> 4, n = i & 15;
        Bs[l][n] = xdbl[(size_t)(b * SEQ + l) * 64 + DTRANK + n];
        Cs[l][n] = xdbl[(size_t)(b * SEQ + l) * 64 + DTRANK + DFF + n];
    }
    __syncthreads();
    float a[16], s[16];
#pragma unroll
    for (int n = 0; n < 16; n++) { a[n] = -__expf(Alog[(size_t)d * 16 + n]); s[n] = 0.f; }
    const float dv = Dp[d];
    for (int l = 0; l < SEQ; l++) {
        const size_t m = (size_t)b * SEQ + l;
        const float dlt = delta[m * DINNER + d];
        const float u = xc[m * DINNER + d];
        const float dbu = dlt * u;
        float acc = 0.f;
#pragma unroll
        for (int n = 0; n < 16; n++) {
            s[n] = __expf(dlt * a[n]) * s[n] + dbu * Bs[l][n];
            acc = fmaf(s[n], Cs[l][n], acc);
        }
        acc = fmaf(u, dv, acc);
        const float r = xr[m * 2048 + DINNER + d];
        y[m * DINNER + d] = acc * (r * sigm(r));
    }
}

// Per (b,k): coeffs[p][q] = sum_r U[p][r]*V[q][r]; preds[b,p] += dot(U[p], t), t[r]=sum_q V[q][r]*in[q].
__global__ __launch_bounds__(256) void coeffs_k(
    const float* __restrict__ outp, const float* __restrict__ inp,
    float* __restrict__ coeffs, float* __restrict__ preds)
{
    const int m = blockIdx.x;          // b*64 + k
    const int b = m >> 6;
    const int tid = threadIdx.x, wave = tid >> 6, lane = tid & 63;
    __shared__ float4 Us[256], Vs[256];
    __shared__ float ins[256];
    __shared__ float4 tpart[4];
    Us[tid] = *(const float4*)(outp + (size_t)m * 2048 + tid * 4);
    Vs[tid] = *(const float4*)(outp + (size_t)m * 2048 + 1024 + tid * 4);
    ins[tid] = inp[(size_t)m * 256 + tid];
    __syncthreads();
    // each lane owns q = 4*lane .. 4*lane+3 (V rows in registers)
    const float4 vq0 = Vs[lane * 4 + 0], vq1 = Vs[lane * 4 + 1];
    const float4 vq2 = Vs[lane * 4 + 2], vq3 = Vs[lane * 4 + 3];
    float* cbase = coeffs + (size_t)m * 65536 + lane * 4;
#pragma unroll 4
    for (int i = 0; i < 64; i++) {
        const int p = (wave << 6) + i;
        const float4 up = Us[p];  // LDS broadcast
        float4 c;
        c.x = up.x * vq0.x + up.y * vq0.y + up.z * vq0.z + up.w * vq0.w;
        c.y = up.x * vq1.x + up.y * vq1.y + up.z * vq1.z + up.w * vq1.w;
        c.z = up.x * vq2.x + up.y * vq2.y + up.z * vq2.z + up.w * vq2.w;
        c.w = up.x * vq3.x + up.y * vq3.y + up.z * vq3.z + up.w * vq3.w;
        *(float4*)(cbase + (size_t)p * 256) = c;   // wave-contiguous 1KB store
    }
    // t[r] = sum_q V[q][r] * in[q]
    const float iv = ins[tid];
    const float4 vm = Vs[tid];
    float4 t = make_float4(vm.x * iv, vm.y * iv, vm.z * iv, vm.w * iv);
#pragma unroll
    for (int off = 32; off > 0; off >>= 1) {
        t.x += __shfl_xor(t.x, off, 64);
        t.y += __shfl_xor(t.y, off, 64);
        t.z += __shfl_xor(t.z, off, 64);
        t.w += __shfl_xor(t.w, off, 64);
    }
    if (lane == 0) tpart[wave] = t;
    __syncthreads();
    const float4 t0 = tpart[0], t1 = tpart[1], t2 = tpart[2], t3 = tpart[3];
    const float4 tt = make_float4(t0.x + t1.x + t2.x + t3.x, t0.y + t1.y + t2.y + t3.y,
                                  t0.z + t1.z + t2.z + t3.z, t0.w + t1.w + t2.w + t3.w);
    const float4 up = Us[tid];
    const float pp = up.x * tt.x + up.y * tt.y + up.z * tt.z + up.w * tt.w;
    atomicAdd(preds + (size_t)b * 256 + tid, pp);
}

} // namespace

extern "C" void kernel_launch(void* const* d_in, const int* in_sizes, int n_in,
                              void* d_out, int out_size, void* d_ws, size_t ws_size,
                              hipStream_t stream)
{
    const float* inputs     = (const float*)d_in[0];
    const float* lin1_w     = (const float*)d_in[1];
    const float* lin1_b     = (const float*)d_in[2];
    const float* lin2_w     = (const float*)d_in[3];
    const float* lin2_b     = (const float*)d_in[4];
    const float* gate_w     = (const float*)d_in[5];
    const float* gate_b     = (const float*)d_in[6];
    const float* sp_norm_w  = (const float*)d_in[7];
    const float* in_proj_w  = (const float*)d_in[8];
    const float* conv_w     = (const float*)d_in[9];
    const float* conv_b     = (const float*)d_in[10];
    const float* x_proj_w   = (const float*)d_in[11];
    const float* dt_proj_w  = (const float*)d_in[12];
    const float* dt_proj_b  = (const float*)d_in[13];
    const float* A_log      = (const float*)d_in[14];
    const float* Dvec       = (const float*)d_in[15];
    const float* out_proj_w = (const float*)d_in[16];
    const float* blk_norm_w = (const float*)d_in[17];
    const float* post_norm_w= (const float*)d_in[18];
    const float* proj_w     = (const float*)d_in[19];

    float* ws = (float*)d_ws;
    float* h     = ws;                 // 1024 x 512
    float* hn    = ws + 524288;        // 1024 x 512
    float* g     = ws + 1048576;       // 1024 x 512
    float* h1    = ws + 1572864;       // 1024 x 512
    float* xr    = ws + 2097152;       // 1024 x 2048 (also reused for final proj out)
    float* xc    = ws + 4194304;       // 1024 x 1024
    float* xdbl  = ws + 5242880;       // 1024 x 64
    float* delta = ws + 5308416;       // 1024 x 1024
    float* y     = ws + 6356992;       // 1024 x 1024
    float* preds  = (float*)d_out;               // 16 x 256
    float* coeffs = (float*)d_out + 4096;        // 16 x 64 x 256 x 256

    const dim3 blk(256);

    // --- spatial preprocessing ---
    gemm_tn<EPI_BIAS_GELU><<<dim3(8, 16), blk, 0, stream>>>(inputs, 256, lin1_w, 256, h1, 512, 256, lin1_b, nullptr);
    gemm_tn<EPI_BIAS_SIGMOID><<<dim3(8, 16), blk, 0, stream>>>(inputs, 256, gate_w, 256, g, 512, 256, gate_b, nullptr);
    gemm_tn<EPI_BIAS_MUL><<<dim3(8, 16), blk, 0, stream>>>(h1, 512, lin2_w, 512, hn, 512, 512, lin2_b, g);
    rmsnorm_k<<<256, blk, 0, stream>>>(hn, sp_norm_w, h);

    // --- mamba layers ---
    for (int l = 0; l < 4; l++) {
        rmsnorm_k<<<256, blk, 0, stream>>>(h, blk_norm_w + l * 512, hn);
        gemm_tn<EPI_NONE><<<dim3(32, 16), blk, 0, stream>>>(hn, 512, in_proj_w + (size_t)l * 2048 * 512, 512, xr, 2048, 512, nullptr, nullptr);
        conv_silu_k<<<4096, blk, 0, stream>>>(xr, conv_w + (size_t)l * 4096, conv_b + l * 1024, xc);
        gemm_tn<EPI_NONE><<<dim3(1, 16), blk, 0, stream>>>(xc, 1024, x_proj_w + (size_t)l * 64 * 1024, 1024, xdbl, 64, 1024, nullptr, nullptr);
        gemm_tn<EPI_BIAS_SOFTPLUS><<<dim3(16, 16), blk, 0, stream>>>(xdbl, 64, dt_proj_w + (size_t)l * 1024 * 32, 32, delta, 1024, 32, dt_proj_b + l * 1024, nullptr);
        scan_k<<<64, blk, 0, stream>>>(xc, delta, xdbl, A_log + (size_t)l * 16384, Dvec + l * 1024, xr, y);
        gemm_tn<EPI_ADD><<<dim3(8, 16), blk, 0, stream>>>(y, 1024, out_proj_w + (size_t)l * 512 * 1024, 1024, h, 512, 1024, nullptr, h);
    }

    // --- final norm + proj + coeffs/preds ---
    rmsnorm_k<<<256, blk, 0, stream>>>(h, post_norm_w, hn);
    gemm_tn<EPI_NONE><<<dim3(32, 16), blk, 0, stream>>>(hn, 512, proj_w, 512, xr, 2048, 512, nullptr, nullptr);
    hipMemsetAsync(d_out, 0, 4096 * sizeof(float), stream);
    coeffs_k<<<1024, blk, 0, stream>>>(xr, inputs, coeffs, preds);
}

// Round 2
// 647.052 us; speedup vs baseline: 1.7320x; 1.7320x over previous
//
#include <hip/hip_runtime.h>
#include <hip/hip_bf16.h>
#include <math.h>

namespace {

constexpr int SEQ    = 64;
constexpr int DINNER = 1024;
constexpr int DFF    = 16;
constexpr int DTRANK = 32;

typedef __attribute__((ext_vector_type(8))) short short8;
typedef __attribute__((ext_vector_type(4))) float f32x4;
typedef __attribute__((address_space(3))) unsigned int lds_u32_t;
typedef __attribute__((address_space(1))) unsigned int glb_u32_t;

__device__ __forceinline__ float sigm(float x) { return 1.f / (1.f + __expf(-x)); }
__device__ __forceinline__ short f2b(float v) {
    __hip_bfloat16 h = __float2bfloat16(v);
    return *(short*)&h;
}

enum { EPI_NONE = 0, EPI_BIAS_GELU, EPI_BIAS_SIGMOID, EPI_BIAS_MUL, EPI_ADD, EPI_BIAS_SOFTPLUS };

// ---------------- fp32 -> bf16 convert ----------------
__global__ __launch_bounds__(256) void f2b_k(const float* __restrict__ in, short* __restrict__ out, int n) {
    const int i = (blockIdx.x * 256 + threadIdx.x) * 4;
    if (i >= n) return;
    const float4 v = *(const float4*)(in + i);
    union { short s[4]; uint2 u; } p;
    p.s[0] = f2b(v.x); p.s[1] = f2b(v.y); p.s[2] = f2b(v.z); p.s[3] = f2b(v.w);
    *(uint2*)(out + i) = p.u;
}

// ---------------- bf16 MFMA GEMM ----------------
// C(1024 x N) = epi(A(1024 x K)bf16 @ W(N x K)bf16^T), fp32 accum.
// Tile BM=128 x BN, BK=32. 256 thr = 4 waves (2x2), wave tile 64 x BN/2.
// LDS linear [row][32] bf16 (64B row stride -> conflict-free frag reads at BK=32).
// Staged with global_load_lds width=16 (bf16 source mandatory).
template <int BN, int EPI, int OUTB>
__global__ __launch_bounds__(256) void mfma_gemm(
    const short* __restrict__ A, int lda,
    const short* __restrict__ W, int ldw,
    void* __restrict__ Cout, int ldc, int Kd,
    const float* __restrict__ bias, const float* __restrict__ extra)
{
    constexpr int NFR = BN / 32;          // n-frags per wave (wave tile n = BN/2)
    __shared__ short As[128 * 32];
    __shared__ short Bs[BN * 32];
    const int tid = threadIdx.x, wave = tid >> 6, lane = tid & 63;
    const int m0 = blockIdx.y * 128, n0 = blockIdx.x * BN;
    const int wm = wave >> 1, wn = wave & 1;
    const int l15 = lane & 15, kg = lane >> 4;

    // staging: chunk p (16B) -> LDS row p>>2, slot p&3; source row-major bf16
    const int pA0 = wave * 128 + lane, pA1 = pA0 + 64;
    const short* srcA0 = A + (size_t)(m0 + (pA0 >> 2)) * lda + (pA0 & 3) * 8;
    const short* srcA1 = A + (size_t)(m0 + (pA1 >> 2)) * lda + (pA1 & 3) * 8;
    short* ldsA0 = As + (size_t)(wave * 128) * 8;
    short* ldsA1 = As + (size_t)(wave * 128 + 64) * 8;

    const short* srcB0; const short* srcB1 = nullptr;
    short* ldsB0; short* ldsB1 = nullptr;
    if constexpr (BN == 128) {
        const int pB0 = wave * 128 + lane, pB1 = pB0 + 64;
        srcB0 = W + (size_t)(n0 + (pB0 >> 2)) * ldw + (pB0 & 3) * 8;
        srcB1 = W + (size_t)(n0 + (pB1 >> 2)) * ldw + (pB1 & 3) * 8;
        ldsB0 = Bs + (size_t)(wave * 128) * 8;
        ldsB1 = Bs + (size_t)(wave * 128 + 64) * 8;
    } else {
        const int pB0 = wave * 64 + lane;
        srcB0 = W + (size_t)(n0 + (pB0 >> 2)) * ldw + (pB0 & 3) * 8;
        ldsB0 = Bs + (size_t)(wave * 64) * 8;
    }

    f32x4 acc[4][NFR] = {};
    for (int k0 = 0; k0 < Kd; k0 += 32) {
        __syncthreads();   // prior iter LDS reads done
        __builtin_amdgcn_global_load_lds((const glb_u32_t*)(srcA0 + k0), (lds_u32_t*)ldsA0, 16, 0, 0);
        __builtin_amdgcn_global_load_lds((const glb_u32_t*)(srcA1 + k0), (lds_u32_t*)ldsA1, 16, 0, 0);
        __builtin_amdgcn_global_load_lds((const glb_u32_t*)(srcB0 + k0), (lds_u32_t*)ldsB0, 16, 0, 0);
        if constexpr (BN == 128)
            __builtin_amdgcn_global_load_lds((const glb_u32_t*)(srcB1 + k0), (lds_u32_t*)ldsB1, 16, 0, 0);
        __syncthreads();   // drains vmcnt before barrier

        short8 af[4], bfr[NFR];
#pragma unroll
        for (int mi = 0; mi < 4; mi++)
            af[mi] = *(const short8*)(As + (wm * 64 + mi * 16 + l15) * 32 + kg * 8);
#pragma unroll
        for (int ni = 0; ni < NFR; ni++)
            bfr[ni] = *(const short8*)(Bs + (wn * (BN / 2) + ni * 16 + l15) * 32 + kg * 8);
#pragma unroll
        for (int mi = 0; mi < 4; mi++)
#pragma unroll
            for (int ni = 0; ni < NFR; ni++)
                acc[mi][ni] = __builtin_amdgcn_mfma_f32_16x16x32_bf16(af[mi], bfr[ni], acc[mi][ni], 0, 0, 0);
    }

    // epilogue: C/D frag mapping col=lane&15, row=(lane>>4)*4+j  [m89]
#pragma unroll
    for (int ni = 0; ni < NFR; ni++) {
        const int col = n0 + wn * (BN / 2) + ni * 16 + l15;
        float b = 0.f;
        if constexpr (EPI == EPI_BIAS_GELU || EPI == EPI_BIAS_SIGMOID || EPI == EPI_BIAS_MUL)
            b = bias[col];
#pragma unroll
        for (int mi = 0; mi < 4; mi++) {
#pragma unroll
            for (int j = 0; j < 4; j++) {
                const int row = m0 + wm * 64 + mi * 16 + kg * 4 + j;
                float v = acc[mi][ni][j];
                if constexpr (EPI == EPI_BIAS_GELU || EPI == EPI_BIAS_SIGMOID || EPI == EPI_BIAS_MUL)
                    v += b;
                if constexpr (EPI == EPI_BIAS_GELU)
                    v = 0.5f * v * (1.f + erff(v * 0.70710678f));
                else if constexpr (EPI == EPI_BIAS_SIGMOID)
                    v = sigm(v);
                else if constexpr (EPI == EPI_BIAS_MUL)
                    v *= extra[(size_t)row * ldc + col];
                else if constexpr (EPI == EPI_ADD)
                    v += extra[(size_t)row * ldc + col];
                if constexpr (OUTB)
                    ((short*)Cout)[(size_t)row * ldc + col] = f2b(v);
                else
                    ((float*)Cout)[(size_t)row * ldc + col] = v;
            }
        }
    }
}

// ---------------- fp32 GEMM (dt_proj only: K=32) ----------------
template <int EPI>
__global__ __launch_bounds__(256) void gemm_tn(
    const float* __restrict__ A, int lda,
    const float* __restrict__ W, int ldw,
    float* __restrict__ C, int ldc, int Kd,
    const float* __restrict__ bias)
{
    __shared__ float As[16][68];
    __shared__ float Bs[16][68];
    const int tid = threadIdx.x;
    const int m0 = blockIdx.y * 64, n0 = blockIdx.x * 64;
    const int row = tid & 63, kg = tid >> 6;
    const int tr = tid >> 4, tc = tid & 15;
    float acc[4][4] = {};
    const float* ap = A + (size_t)(m0 + row) * lda + kg * 4;
    const float* wp = W + (size_t)(n0 + row) * ldw + kg * 4;
    for (int k0 = 0; k0 < Kd; k0 += 16) {
        const float4 a4 = *(const float4*)(ap + k0);
        const float4 b4 = *(const float4*)(wp + k0);
        __syncthreads();
        As[kg * 4 + 0][row] = a4.x; As[kg * 4 + 1][row] = a4.y;
        As[kg * 4 + 2][row] = a4.z; As[kg * 4 + 3][row] = a4.w;
        Bs[kg * 4 + 0][row] = b4.x; Bs[kg * 4 + 1][row] = b4.y;
        Bs[kg * 4 + 2][row] = b4.z; Bs[kg * 4 + 3][row] = b4.w;
        __syncthreads();
#pragma unroll
        for (int k = 0; k < 16; k++) {
            const float4 av = *(const float4*)&As[k][tr * 4];
            const float4 bv = *(const float4*)&Bs[k][tc * 4];
#pragma unroll
            for (int i = 0; i < 4; i++) {
                const float a = (&av.x)[i];
                acc[i][0] = fmaf(a, bv.x, acc[i][0]);
                acc[i][1] = fmaf(a, bv.y, acc[i][1]);
                acc[i][2] = fmaf(a, bv.z, acc[i][2]);
                acc[i][3] = fmaf(a, bv.w, acc[i][3]);
            }
        }
    }
#pragma unroll
    for (int i = 0; i < 4; i++) {
        const int mm = m0 + tr * 4 + i;
        const int nn = n0 + tc * 4;
        float4 v = make_float4(acc[i][0], acc[i][1], acc[i][2], acc[i][3]);
        if (EPI == EPI_BIAS_SOFTPLUS) {
            const float4 b = *(const float4*)(bias + nn);
            v.x += b.x; v.y += b.y; v.z += b.z; v.w += b.w;
            v.x = fmaxf(v.x, 0.f) + log1pf(__expf(-fabsf(v.x)));
            v.y = fmaxf(v.y, 0.f) + log1pf(__expf(-fabsf(v.y)));
            v.z = fmaxf(v.z, 0.f) + log1pf(__expf(-fabsf(v.z)));
            v.w = fmaxf(v.w, 0.f) + log1pf(__expf(-fabsf(v.w)));
        }
        *(float4*)(C + (size_t)mm * ldc + nn) = v;
    }
}

// ---------------- rmsnorm (rows of 512), OUTB: bf16 out ----------------
template <int OUTB>
__global__ __launch_bounds__(256) void rmsnorm_k(
    const float* __restrict__ in, const float* __restrict__ w, void* __restrict__ out)
{
    const int lane = threadIdx.x & 63;
    const int rowId = blockIdx.x * 4 + (threadIdx.x >> 6);
    const float* ip = in + (size_t)rowId * 512 + lane * 8;
    const float4 v1 = *(const float4*)ip;
    const float4 v2 = *(const float4*)(ip + 4);
    float ss = v1.x * v1.x + v1.y * v1.y + v1.z * v1.z + v1.w * v1.w
             + v2.x * v2.x + v2.y * v2.y + v2.z * v2.z + v2.w * v2.w;
#pragma unroll
    for (int off = 32; off > 0; off >>= 1) ss += __shfl_xor(ss, off, 64);
    const float rs = rsqrtf(ss * (1.f / 512.f) + 1e-5f);
    const float4 w1 = *(const float4*)(w + lane * 8);
    const float4 w2 = *(const float4*)(w + lane * 8 + 4);
    const float o[8] = { v1.x * rs * w1.x, v1.y * rs * w1.y, v1.z * rs * w1.z, v1.w * rs * w1.w,
                         v2.x * rs * w2.x, v2.y * rs * w2.y, v2.z * rs * w2.z, v2.w * rs * w2.w };
    if constexpr (OUTB) {
        short8 p;
#pragma unroll
        for (int i = 0; i < 8; i++) p[i] = f2b(o[i]);
        *(short8*)((short*)out + (size_t)rowId * 512 + lane * 8) = p;
    } else {
        float* op = (float*)out + (size_t)rowId * 512 + lane * 8;
        *(float4*)op       = make_float4(o[0], o[1], o[2], o[3]);
        *(float4*)(op + 4) = make_float4(o[4], o[5], o[6], o[7]);
    }
}

// ---------------- depthwise causal conv + silu; dual fp32/bf16 out ----------------
__global__ __launch_bounds__(256) void conv_silu_k(
    const float* __restrict__ xr, const float* __restrict__ cw,
    const float* __restrict__ cb, float* __restrict__ xc, short* __restrict__ xcb)
{
    const int idx = blockIdx.x * 256 + threadIdx.x;
    const int d = idx & (DINNER - 1);
    const int m = idx >> 10;
    const int l = m & (SEQ - 1);
    const float4 w4 = *(const float4*)(cw + d * 4);
    const float wj[4] = { w4.x, w4.y, w4.z, w4.w };
    float acc = cb[d];
#pragma unroll
    for (int j = 0; j < 4; j++) {
        const int li = l + j - 3;
        if (li >= 0) acc += xr[(size_t)(m + j - 3) * 2048 + d] * wj[j];
    }
    const float v = acc * sigm(acc);
    xc[idx] = v;
    xcb[idx] = f2b(v);
}

// ---------------- selective scan + fused silu(res) gate; bf16 out ----------------
__global__ __launch_bounds__(256) void scan_k(
    const float* __restrict__ xc, const float* __restrict__ delta,
    const float* __restrict__ xdbl, const float* __restrict__ Alog,
    const float* __restrict__ Dp, const float* __restrict__ xr, short* __restrict__ yb)
{
    const int b = blockIdx.x >> 2;
    const int d = ((blockIdx.x & 3) << 8) + threadIdx.x;
    __shared__ float Bsh[SEQ][DFF];
    __shared__ float Csh[SEQ][DFF];
    for (int i = threadIdx.x; i < SEQ * DFF; i += 256) {
        const int l = i >> 4, n = i & 15;
        Bsh[l][n] = xdbl[(size_t)(b * SEQ + l) * 64 + DTRANK + n];
        Csh[l][n] = xdbl[(size_t)(b * SEQ + l) * 64 + DTRANK + DFF + n];
    }
    __syncthreads();
    float a[16], s[16];
#pragma unroll
    for (int n = 0; n < 16; n++) { a[n] = -__expf(Alog[(size_t)d * 16 + n]); s[n] = 0.f; }
    const float dv = Dp[d];
    for (int l = 0; l < SEQ; l++) {
        const size_t m = (size_t)b * SEQ + l;
        const float dlt = delta[m * DINNER + d];
        const float u = xc[m * DINNER + d];
        const float dbu = dlt * u;
        float acc = 0.f;
#pragma unroll
        for (int n = 0; n < 16; n++) {
            s[n] = __expf(dlt * a[n]) * s[n] + dbu * Bsh[l][n];
            acc = fmaf(s[n], Csh[l][n], acc);
        }
        acc = fmaf(u, dv, acc);
        const float r = xr[m * 2048 + DINNER + d];
        yb[m * DINNER + d] = f2b(acc * (r * sigm(r)));
    }
}

// ---------------- coeffs + preds ----------------
__global__ __launch_bounds__(256) void coeffs_k(
    const float* __restrict__ outp, const float* __restrict__ inp,
    float* __restrict__ coeffs, float* __restrict__ preds)
{
    const int m = blockIdx.x;
    const int b = m >> 6;
    const int tid = threadIdx.x, wave = tid >> 6, lane = tid & 63;
    __shared__ float4 Us[256], Vs[256];
    __shared__ float ins[256];
    __shared__ float4 tpart[4];
    Us[tid] = *(const float4*)(outp + (size_t)m * 2048 + tid * 4);
    Vs[tid] = *(const float4*)(outp + (size_t)m * 2048 + 1024 + tid * 4);
    ins[tid] = inp[(size_t)m * 256 + tid];
    __syncthreads();
    const float4 vq0 = Vs[lane * 4 + 0], vq1 = Vs[lane * 4 + 1];
    const float4 vq2 = Vs[lane * 4 + 2], vq3 = Vs[lane * 4 + 3];
    float* cbase = coeffs + (size_t)m * 65536 + lane * 4;
#pragma unroll 4
    for (int i = 0; i < 64; i++) {
        const int p = (wave << 6) + i;
        const float4 up = Us[p];
        float4 c;
        c.x = up.x * vq0.x + up.y * vq0.y + up.z * vq0.z + up.w * vq0.w;
        c.y = up.x * vq1.x + up.y * vq1.y + up.z * vq1.z + up.w * vq1.w;
        c.z = up.x * vq2.x + up.y * vq2.y + up.z * vq2.z + up.w * vq2.w;
        c.w = up.x * vq3.x + up.y * vq3.y + up.z * vq3.z + up.w * vq3.w;
        *(float4*)(cbase + (size_t)p * 256) = c;
    }
    const float iv = ins[tid];
    const float4 vm = Vs[tid];
    float4 t = make_float4(vm.x * iv, vm.y * iv, vm.z * iv, vm.w * iv);
#pragma unroll
    for (int off = 32; off > 0; off >>= 1) {
        t.x += __shfl_xor(t.x, off, 64);
        t.y += __shfl_xor(t.y, off, 64);
        t.z += __shfl_xor(t.z, off, 64);
        t.w += __shfl_xor(t.w, off, 64);
    }
    if (lane == 0) tpart[wave] = t;
    __syncthreads();
    const float4 t0 = tpart[0], t1 = tpart[1], t2 = tpart[2], t3 = tpart[3];
    const float4 tt = make_float4(t0.x + t1.x + t2.x + t3.x, t0.y + t1.y + t2.y + t3.y,
                                  t0.z + t1.z + t2.z + t3.z, t0.w + t1.w + t2.w + t3.w);
    const float4 up = Us[tid];
    const float pp = up.x * tt.x + up.y * tt.y + up.z * tt.z + up.w * tt.w;
    atomicAdd(preds + (size_t)b * 256 + tid, pp);
}

} // namespace

extern "C" void kernel_launch(void* const* d_in, const int* in_sizes, int n_in,
                              void* d_out, int out_size, void* d_ws, size_t ws_size,
                              hipStream_t stream)
{
    const float* inputs     = (const float*)d_in[0];
    const float* lin1_w     = (const float*)d_in[1];
    const float* lin1_b     = (const float*)d_in[2];
    const float* lin2_w     = (const float*)d_in[3];
    const float* lin2_b     = (const float*)d_in[4];
    const float* gate_w     = (const float*)d_in[5];
    const float* gate_b     = (const float*)d_in[6];
    const float* sp_norm_w  = (const float*)d_in[7];
    const float* in_proj_w  = (const float*)d_in[8];
    const float* conv_w     = (const float*)d_in[9];
    const float* conv_b     = (const float*)d_in[10];
    const float* x_proj_w   = (const float*)d_in[11];
    const float* dt_proj_w  = (const float*)d_in[12];
    const float* dt_proj_b  = (const float*)d_in[13];
    const float* A_log      = (const float*)d_in[14];
    const float* Dvec       = (const float*)d_in[15];
    const float* out_proj_w = (const float*)d_in[16];
    const float* blk_norm_w = (const float*)d_in[17];
    const float* post_norm_w= (const float*)d_in[18];
    const float* proj_w     = (const float*)d_in[19];

    float* ws = (float*)d_ws;
    float* h     = ws;                  // 1024 x 512
    float* xr    = ws + 524288;         // 1024 x 2048
    float* xc    = ws + 2621440;        // 1024 x 1024 (aliases spatial hn)
    float* delta = ws + 3670016;        // 1024 x 1024 (aliases spatial g)
    float* xdbl  = ws + 4718592;        // 1024 x 64
    short* bfb   = (short*)(ws + 4784128);
    short* inputsb = bfb;               // 1024 x 256
    short* hnb     = bfb + 262144;      // 1024 x 512
    short* xcb     = bfb + 786432;      // 1024 x 1024
    short* yb      = bfb + 1835008;     // 1024 x 1024 (aliases spatial h1b)
    short* wlin1b  = bfb + 2883584;     // 512 x 256
    short* wgateb  = bfb + 3014656;     // 512 x 256
    short* wlin2b  = bfb + 3145728;     // 512 x 512
    short* winpb   = bfb + 3407872;     // 4 x 2048 x 512
    short* wxpb    = bfb + 7602176;     // 4 x 64 x 1024
    short* woutpb  = bfb + 7864320;     // 4 x 512 x 1024
    short* wprojb  = bfb + 9961472;     // 2048 x 512
    float* preds  = (float*)d_out;
    float* coeffs = (float*)d_out + 4096;

    const dim3 blk(256);
    auto cvt = [&](const float* src, short* dst, int n) {
        f2b_k<<<dim3((n / 4 + 255) / 256), blk, 0, stream>>>(src, dst, n);
    };

    // weight / input conversions (graph-safe, every launch)
    cvt(lin1_w, wlin1b, 131072);
    cvt(gate_w, wgateb, 131072);
    cvt(lin2_w, wlin2b, 262144);
    cvt(in_proj_w, winpb, 4194304);
    cvt(x_proj_w, wxpb, 262144);
    cvt(out_proj_w, woutpb, 2097152);
    cvt(proj_w, wprojb, 1048576);
    cvt(inputs, inputsb, 262144);

    // --- spatial preprocessing ---
    mfma_gemm<128, EPI_BIAS_GELU, 1><<<dim3(4, 8), blk, 0, stream>>>(
        inputsb, 256, wlin1b, 256, yb /*h1b*/, 512, 256, lin1_b, nullptr);
    mfma_gemm<128, EPI_BIAS_SIGMOID, 0><<<dim3(4, 8), blk, 0, stream>>>(
        inputsb, 256, wgateb, 256, delta /*g*/, 512, 256, gate_b, nullptr);
    mfma_gemm<128, EPI_BIAS_MUL, 0><<<dim3(4, 8), blk, 0, stream>>>(
        yb, 512, wlin2b, 512, xc /*hn*/, 512, 512, lin2_b, delta);
    rmsnorm_k<0><<<256, blk, 0, stream>>>(xc, sp_norm_w, h);

    // --- mamba layers ---
    for (int l = 0; l < 4; l++) {
        rmsnorm_k<1><<<256, blk, 0, stream>>>(h, blk_norm_w + l * 512, hnb);
        mfma_gemm<128, EPI_NONE, 0><<<dim3(16, 8), blk, 0, stream>>>(
            hnb, 512, winpb + (size_t)l * 1048576, 512, xr, 2048, 512, nullptr, nullptr);
        conv_silu_k<<<4096, blk, 0, stream>>>(xr, conv_w + (size_t)l * 4096, conv_b + l * 1024, xc, xcb);
        mfma_gemm<64, EPI_NONE, 0><<<dim3(1, 8), blk, 0, stream>>>(
            xcb, 1024, wxpb + (size_t)l * 65536, 1024, xdbl, 64, 1024, nullptr, nullptr);
        gemm_tn<EPI_BIAS_SOFTPLUS><<<dim3(16, 16), blk, 0, stream>>>(
            xdbl, 64, dt_proj_w + (size_t)l * 32768, 32, delta, 1024, 32, dt_proj_b + l * 1024);
        scan_k<<<64, blk, 0, stream>>>(xc, delta, xdbl, A_log + (size_t)l * 16384, Dvec + l * 1024, xr, yb);
        mfma_gemm<128, EPI_ADD, 0><<<dim3(4, 8), blk, 0, stream>>>(
            yb, 1024, woutpb + (size_t)l * 524288, 1024, h, 512, 1024, nullptr, h);
    }

    // --- final norm + proj + coeffs/preds ---
    rmsnorm_k<1><<<256, blk, 0, stream>>>(h, post_norm_w, hnb);
    mfma_gemm<128, EPI_NONE, 0><<<dim3(16, 8), blk, 0, stream>>>(
        hnb, 512, wprojb, 512, xr, 2048, 512, nullptr, nullptr);
    hipMemsetAsync(d_out, 0, 4096 * sizeof(float), stream);
    coeffs_k<<<1024, blk, 0, stream>>>(xr, inputs, coeffs, preds);
}